// Round 7
// baseline (342.856 us; speedup 1.0000x reference)
//
#include <hip/hip_runtime.h>
#include <hip/hip_bf16.h>

#define BATCH 64
#define CDIM  256
#define MHW   196
#define MP    224      // padded K for covariance (multiple of 32)
#define EDIM  512
#define CC    65536    // CDIM*CDIM
#define NU    36       // upper-triangle 32x32 units of a 256x256 matrix (8x8 grid)
#define WCONV_BLOCKS 2048   // 2048 * 16384 = 33,554,432 = CC*EDIM f32 elements

typedef __attribute__((ext_vector_type(8))) short short8_t;   // 8 x bf16 MFMA frag
typedef __attribute__((ext_vector_type(4))) float f32x4;

static __device__ __forceinline__ unsigned short f2bfu(float f) {
    __hip_bfloat16 h = __float2bfloat16(f);
    return __builtin_bit_cast(unsigned short, h);
}

// unit t -> (ui,uj) upper-triangle coords on the 8x8 grid of 32x32 units
__device__ static const unsigned char UI36[NU] = {
    0,0,0,0,0,0,0,0, 1,1,1,1,1,1,1, 2,2,2,2,2,2, 3,3,3,3,3, 4,4,4,4, 5,5,5, 6,6, 7};
__device__ static const unsigned char UJ36[NU] = {
    0,1,2,3,4,5,6,7, 1,2,3,4,5,6,7, 2,3,4,5,6,7, 3,4,5,6,7, 4,5,6,7, 5,6,7, 6,7, 7};

// ---------------------------------------------------------------------------
// center_row: one wave centers one local row (0..255) of batch b,
// bf16-cast (pad to MP), per-row sum-of-squares -> rs[row] (LDS).
// ---------------------------------------------------------------------------
static __device__ __forceinline__ void center_row(
    const float* __restrict__ feat_b, __hip_bfloat16* __restrict__ xcb_b,
    float* __restrict__ rs, int row, int l)
{
    const float* src = feat_b + (size_t)row * MHW;
    float v0 = src[l];
    float v1 = src[l + 64];
    float v2 = src[l + 128];
    float v3 = (l + 192 < MHW) ? src[l + 192] : 0.0f;
    float s = v0 + v1 + v2 + v3;
    #pragma unroll
    for (int o = 32; o >= 1; o >>= 1) s += __shfl_xor(s, o, 64);
    const float mean = s * (1.0f / MHW);
    v0 -= mean; v1 -= mean; v2 -= mean;
    v3 = (l + 192 < MHW) ? (v3 - mean) : 0.0f;
    float sq = v0*v0 + v1*v1 + v2*v2 + v3*v3;
    #pragma unroll
    for (int o = 32; o >= 1; o >>= 1) sq += __shfl_xor(sq, o, 64);
    if (l == 0) rs[row] = sq;
    __hip_bfloat16* dst = xcb_b + (size_t)row * MP;
    dst[l]       = __float2bfloat16(v0);
    dst[l + 64]  = __float2bfloat16(v1);
    dst[l + 128] = __float2bfloat16(v2);
    if (l + 192 < MP) dst[l + 192] = __float2bfloat16(v3);   // zero pad to MP
}

// ---------------------------------------------------------------------------
// mm32: one wave computes one 32x32 unit (ui,uj) of
// out = a*(A@B) + beta*D + gamma*I (per-batch pointers; A/B stride KT,
// D/out stride 256). Operands stored exactly symmetric (mirror writes), so
// row-reads of B give B^T columns. acc[2][2] = 16 f32 -> no spill at the
// 1024-thread 128-VGPR budget (round-6 failure: acc[4][4] spilled @64 VGPR).
// ---------------------------------------------------------------------------
template<int KT, bool NORM>
static __device__ __forceinline__ float mm32(
    const __hip_bfloat16* __restrict__ A, const __hip_bfloat16* __restrict__ Bm,
    const __hip_bfloat16* __restrict__ D, __hip_bfloat16* __restrict__ out,
    float a, float beta, float gamma, int ui, int uj, int l)
{
    const int lr = l & 15, lg = l >> 4;

    f32x4 acc[2][2];
    #pragma unroll
    for (int i = 0; i < 2; i++)
        #pragma unroll
        for (int j = 0; j < 2; j++)
            #pragma unroll
            for (int r = 0; r < 4; r++) acc[i][j][r] = 0.0f;

    const __hip_bfloat16* Ab = A  + (size_t)(ui * 32 + lr) * KT;
    const __hip_bfloat16* Bb = Bm + (size_t)(uj * 32 + lr) * KT;
    for (int k0 = 0; k0 < KT; k0 += 32) {
        const int k = k0 + lg * 8;
        short8_t af[2], bfr[2];
        #pragma unroll
        for (int i = 0; i < 2; i++)
            af[i] = *reinterpret_cast<const short8_t*>(Ab + (size_t)i * 16 * KT + k);
        #pragma unroll
        for (int j = 0; j < 2; j++)
            bfr[j] = *reinterpret_cast<const short8_t*>(Bb + (size_t)j * 16 * KT + k);
        #pragma unroll
        for (int i = 0; i < 2; i++)
            #pragma unroll
            for (int j = 0; j < 2; j++)
                acc[i][j] = __builtin_amdgcn_mfma_f32_16x16x32_bf16(af[i], bfr[j], acc[i][j], 0, 0, 0);
    }

    float ns = 0.0f;
    #pragma unroll
    for (int i = 0; i < 2; i++) {
        #pragma unroll
        for (int j = 0; j < 2; j++) {
            #pragma unroll
            for (int r = 0; r < 4; r++) {
                const int grow = ui * 32 + i * 16 + lg * 4 + r;
                const int gcol = uj * 32 + j * 16 + lr;
                float v = a * acc[i][j][r];
                if (D) v += beta * __bfloat162float(D[grow * 256 + gcol]);
                if (grow == gcol) v += gamma;
                const __hip_bfloat16 hv = __float2bfloat16(v);
                out[grow * 256 + gcol] = hv;
                if (ui != uj) out[gcol * 256 + grow] = hv;   // exact-symmetry mirror
                if (NORM) {
                    const float fv = __bfloat162float(hv);
                    ns += ((ui != uj) ? 2.0f : 1.0f) * fv * fv;
                }
            }
        }
    }
    return ns;
}

// step: all 16 waves sweep the 36 units (t = w, w+16, w+32)
template<int KT, bool NORM>
static __device__ __forceinline__ float ns_step(
    const __hip_bfloat16* A, const __hip_bfloat16* Bm,
    const __hip_bfloat16* D, __hip_bfloat16* out,
    float a, float beta, float gamma, int w, int l)
{
    float ns = 0.0f;
    for (int t = w; t < NU; t += 16)
        ns += mm32<KT, NORM>(A, Bm, D, out, a, beta, gamma, UI36[t], UJ36[t], l);
    return ns;
}

// ---------------------------------------------------------------------------
// k_mega: blocks 0..63 = full per-batch NS chain on one CU (16 waves,
// __syncthreads between steps only — grid.sync costs more than a launch,
// round 5). Blocks 64.. = W f32->bf16 conversion, overlapped (independent).
// __launch_bounds__(1024,4): 1 block/CU, VGPR cap 128 -> mm32 (~70 live) fits.
// ---------------------------------------------------------------------------
__global__ __launch_bounds__(1024, 4) void k_mega(
    const float* __restrict__ feat, const float* __restrict__ W,
    __hip_bfloat16* __restrict__ xcb_all, __hip_bfloat16* __restrict__ Wbf,
    __hip_bfloat16* __restrict__ M0, __hip_bfloat16* __restrict__ M1,
    __hip_bfloat16* __restrict__ M2, __hip_bfloat16* __restrict__ M3,
    __hip_bfloat16* __restrict__ M4, float* __restrict__ nrm)
{
    const int tid = threadIdx.x, w = tid >> 6, l = tid & 63;

    if (blockIdx.x >= BATCH) {
        // ---- W conversion: 16384 f32 per block, coalesced x4 ----
        const size_t base = (size_t)(blockIdx.x - BATCH) * 16384;
        #pragma unroll
        for (int it = 0; it < 4; ++it) {
            const size_t idx = base + (size_t)it * 4096 + (size_t)tid * 4;
            const f32x4 v = *reinterpret_cast<const f32x4*>(W + idx);
            ushort4 o;
            o.x = f2bfu(v[0]); o.y = f2bfu(v[1]); o.z = f2bfu(v[2]); o.w = f2bfu(v[3]);
            *reinterpret_cast<ushort4*>(Wbf + idx) = o;
        }
        return;
    }

    __shared__ float rs[256];
    __shared__ float red[16];
    __shared__ float s_alpha;

    const int b = blockIdx.x;
    const float* feat_b = feat + (size_t)b * CDIM * MHW;
    __hip_bfloat16* xcb = xcb_all + (size_t)b * CDIM * MP;
    __hip_bfloat16* m0 = M0 + (size_t)b * CC;
    __hip_bfloat16* m1 = M1 + (size_t)b * CC;
    __hip_bfloat16* m2 = M2 + (size_t)b * CC;
    __hip_bfloat16* m3 = M3 + (size_t)b * CC;
    __hip_bfloat16* m4 = M4 + (size_t)b * CC;

    // phase 0: center 256 rows (16 waves x 16 rows)
    #pragma unroll
    for (int it = 0; it < 16; ++it)
        center_row(feat_b, xcb, rs, it * 16 + w, l);
    __syncthreads();

    // trace = sum(rs) -> s_alpha = 1/tr
    if (tid < 256) {
        float v = rs[tid];
        #pragma unroll
        for (int o = 32; o >= 1; o >>= 1) v += __shfl_xor(v, o, 64);
        if (l == 0) red[tid >> 6] = v;
    }
    __syncthreads();
    if (tid == 0) s_alpha = 1.0f / (red[0] + red[1] + red[2] + red[3]);
    __syncthreads();
    const float ia = s_alpha;

    // y  = (1/tr) * xc @ xc^T                         -> M0
    ns_step<MP,  false>(xcb, xcb, nullptr, m0, ia, 0.0f, 0.0f, w, l);
    __syncthreads();
    // Y1 = -0.5*y@y + 1.5*y                           -> M1
    ns_step<256, false>(m0, m0, m0, m1, -0.5f, 1.5f, 0.0f, w, l);
    __syncthreads();
    // T2 = 0.5*y@Y1 - 1.5*Y1 + 3I                     -> M2
    ns_step<256, false>(m0, m1, m1, m2, 0.5f, -1.5f, 3.0f, w, l);
    __syncthreads();
    // Y2 = 0.5*Y1@T2 -> M3 ; Z2 = -0.25*T2@y + 0.75*T2 -> M4  (independent)
    ns_step<256, false>(m1, m2, nullptr, m3, 0.5f, 0.0f, 0.0f, w, l);
    ns_step<256, false>(m2, m0, m2, m4, -0.25f, 0.75f, 0.0f, w, l);
    __syncthreads();
    // T3 = -Z2@Y2 + 3I                                -> M1 (Y1 dead)
    ns_step<256, false>(m4, m3, nullptr, m1, -1.0f, 0.0f, 3.0f, w, l);
    __syncthreads();
    // Y3 = 0.5*Y2@T3  (+ Frobenius norm^2)            -> M2 (T2 dead)
    float ns = ns_step<256, true>(m3, m1, nullptr, m2, 0.5f, 0.0f, 0.0f, w, l);
    #pragma unroll
    for (int o = 32; o >= 1; o >>= 1) ns += __shfl_xor(ns, o, 64);
    __syncthreads();
    if (l == 0) red[w] = ns;
    __syncthreads();
    if (tid == 0) {
        float f = 0.0f;
        #pragma unroll
        for (int q = 0; q < 16; ++q) f += red[q];
        nrm[b] = f;
    }
}

// ---------------------------------------------------------------------------
// k_proj2: u[b,e] = sum_k flat[b,k]*Wbf[e,k]; split-K (64 ksplits x 8 etiles),
// block K-chunk 1024 (4 waves x 256), cross-wave LDS reduce -> upart[ks].
// W already bf16 -> half the HBM traffic of f32 W.
// ---------------------------------------------------------------------------
__global__ __launch_bounds__(256) void k_proj2(const __hip_bfloat16* __restrict__ flat,
                                               const __hip_bfloat16* __restrict__ Wbf,
                                               float* __restrict__ upart)
{
    __shared__ float racc[2][64][65];
    const int ks = blockIdx.x, et = blockIdx.y;
    const int tid = threadIdx.x, wv = tid >> 6, l = tid & 63;
    const int lr = l & 15, lg = l >> 4;
    const int kbase = ks * 1024 + wv * 256;

    f32x4 acc[4][4];
    #pragma unroll
    for (int i = 0; i < 4; i++)
        #pragma unroll
        for (int j = 0; j < 4; j++)
            #pragma unroll
            for (int r = 0; r < 4; r++) acc[i][j][r] = 0.0f;

    for (int kk = 0; kk < 256; kk += 32) {
        const int k = kbase + kk + lg * 8;
        short8_t af[4], bfr[4];
        #pragma unroll
        for (int i = 0; i < 4; i++)
            af[i] = *reinterpret_cast<const short8_t*>(flat + (size_t)(i * 16 + lr) * CC + k);
        #pragma unroll
        for (int j = 0; j < 4; j++)
            bfr[j] = *reinterpret_cast<const short8_t*>(Wbf + (size_t)(et * 64 + j * 16 + lr) * CC + k);
        #pragma unroll
        for (int i = 0; i < 4; i++)
            #pragma unroll
            for (int j = 0; j < 4; j++)
                acc[i][j] = __builtin_amdgcn_mfma_f32_16x16x32_bf16(af[i], bfr[j], acc[i][j], 0, 0, 0);
    }

    if (wv >= 2) {
        #pragma unroll
        for (int i = 0; i < 4; i++)
            #pragma unroll
            for (int j = 0; j < 4; j++)
                #pragma unroll
                for (int r = 0; r < 4; r++)
                    racc[wv - 2][i * 16 + lg * 4 + r][j * 16 + lr] = acc[i][j][r];
    }
    __syncthreads();
    if (wv < 2) {
        #pragma unroll
        for (int i = 0; i < 4; i++)
            #pragma unroll
            for (int j = 0; j < 4; j++)
                #pragma unroll
                for (int r = 0; r < 4; r++)
                    racc[wv][i * 16 + lg * 4 + r][j * 16 + lr] += acc[i][j][r];
    }
    __syncthreads();
    float* ub = upart + (size_t)ks * (64 * EDIM);
    #pragma unroll
    for (int q = 0; q < 16; q++) {
        const int idx = q * 256 + tid;
        const int x = idx >> 6, y = idx & 63;
        ub[(size_t)x * EDIM + et * 64 + y] = racc[0][x][y] + racc[1][x][y];
    }
}

// ---------------------------------------------------------------------------
// k_fin: reduce 64 K-partials, 1/||Y3||_F scale, +bias, BN, final L2 norm.
// ---------------------------------------------------------------------------
__global__ __launch_bounds__(256) void k_fin(const float* __restrict__ upart,
                                             const float* __restrict__ nrm,
                                             const float* __restrict__ bias,
                                             const float* __restrict__ gma,
                                             const float* __restrict__ bta,
                                             const float* __restrict__ mu,
                                             const float* __restrict__ var,
                                             float* __restrict__ out)
{
    __shared__ float wsum[4];
    const int bb = blockIdx.x;
    const int tid = threadIdx.x, wv = tid >> 6, l = tid & 63;
    const int e0 = tid, e1 = tid + 256;
    float u0 = 0.0f, u1 = 0.0f;
    for (int p = 0; p < 64; ++p) {
        const float* up = upart + ((size_t)p * 64 + bb) * EDIM;
        u0 += up[e0]; u1 += up[e1];
    }
    const float s = 1.0f / fmaxf(sqrtf(nrm[bb]), 1e-12f);
    const float emb0 = s * u0 + bias[e0];
    const float emb1 = s * u1 + bias[e1];
    const float v0 = (emb0 - mu[e0]) * rsqrtf(var[e0] + 1e-5f) * gma[e0] + bta[e0];
    const float v1 = (emb1 - mu[e1]) * rsqrtf(var[e1] + 1e-5f) * gma[e1] + bta[e1];
    float sq = v0 * v0 + v1 * v1;
    #pragma unroll
    for (int o = 32; o >= 1; o >>= 1) sq += __shfl_xor(sq, o, 64);
    if (l == 0) wsum[wv] = sq;
    __syncthreads();
    const float tot = wsum[0] + wsum[1] + wsum[2] + wsum[3];
    const float rn = 1.0f / fmaxf(sqrtf(tot), 1e-12f);
    out[(size_t)bb * EDIM + e0] = v0 * rn;
    out[(size_t)bb * EDIM + e1] = v1 * rn;
}

// ---------------------------------------------------------------------------
extern "C" void kernel_launch(void* const* d_in, const int* in_sizes, int n_in,
                              void* d_out, int out_size, void* d_ws, size_t ws_size,
                              hipStream_t stream)
{
    const float* feat = (const float*)d_in[0];
    const float* W    = (const float*)d_in[1];
    const float* bias = (const float*)d_in[2];
    const float* gma  = (const float*)d_in[3];
    const float* bta  = (const float*)d_in[4];
    const float* mu   = (const float*)d_in[5];
    const float* var  = (const float*)d_in[6];
    float* out = (float*)d_out;

    char* ws = (char*)d_ws;
    constexpr size_t XCB_BYTES = (size_t)BATCH * CDIM * MP * 2;     //  7,340,032
    constexpr size_t MATB      = (size_t)BATCH * CC * 2;            //  8,388,608
    constexpr size_t WBF_BYTES = (size_t)CC * EDIM * 2;             // 67,108,864
    constexpr size_t OFF_XCB   = 4096;
    constexpr size_t OFF_M     = OFF_XCB + XCB_BYTES;
    constexpr size_t OFF_WBF   = OFF_M + 5 * MATB;
    constexpr size_t OFF_UP    = OFF_WBF + WBF_BYTES;
    constexpr size_t NEEDED    = OFF_UP + (size_t)64 * 64 * EDIM * 4;  // ~125 MB
    if (ws_size < NEEDED) return;

    float* nrm = (float*)(ws + 0);                                   // 64 floats
    __hip_bfloat16* xcb = (__hip_bfloat16*)(ws + OFF_XCB);
    __hip_bfloat16* M0  = (__hip_bfloat16*)(ws + OFF_M + 0 * MATB);
    __hip_bfloat16* M1  = (__hip_bfloat16*)(ws + OFF_M + 1 * MATB);
    __hip_bfloat16* M2  = (__hip_bfloat16*)(ws + OFF_M + 2 * MATB);
    __hip_bfloat16* M3  = (__hip_bfloat16*)(ws + OFF_M + 3 * MATB);
    __hip_bfloat16* M4  = (__hip_bfloat16*)(ws + OFF_M + 4 * MATB);
    __hip_bfloat16* Wbf = (__hip_bfloat16*)(ws + OFF_WBF);
    float* upart = (float*)(ws + OFF_UP);

    k_mega<<<dim3(BATCH + WCONV_BLOCKS), dim3(1024), 0, stream>>>(
        feat, W, xcb, Wbf, M0, M1, M2, M3, M4, nrm);
    k_proj2<<<dim3(64, 8), dim3(256), 0, stream>>>(M2, Wbf, upart);
    k_fin<<<dim3(64), dim3(256), 0, stream>>>(upart, nrm, bias, gma, bta, mu, var, out);
}

// Round 8
// 157.785 us; speedup vs baseline: 2.1729x; 2.1729x over previous
//
#include <hip/hip_runtime.h>
#include <hip/hip_bf16.h>

#define BATCH 64
#define CDIM  256
#define MHW   196
#define MP    224      // padded K for covariance (multiple of 32)
#define EDIM  512
#define CC    65536    // CDIM*CDIM
#define NTRI  10       // upper-triangle 64x64 tiles of a 256x256 matrix
#define NMM   (BATCH * NTRI)   // 640 mm blocks per step
#define NCONV_TOTAL 2048       // 2048 blocks x 16384 f32 = CC*EDIM

typedef __attribute__((ext_vector_type(8))) short short8_t;   // 8 x bf16 MFMA frag
typedef __attribute__((ext_vector_type(4))) float f32x4;
typedef __attribute__((ext_vector_type(4))) unsigned int u32x4;

static __device__ __forceinline__ unsigned short f2bfu(float f) {
    __hip_bfloat16 h = __float2bfloat16(f);
    return __builtin_bit_cast(unsigned short, h);
}

struct MMOp {
    const __hip_bfloat16* A;
    const __hip_bfloat16* B;
    const __hip_bfloat16* D;
    __hip_bfloat16*       out;
    const float*          alpha_ptr;   // mode!=0: rowsq base, a = alpha_c / sum256
    int                   alpha_mode;
    float                 alpha_c, beta, gamma;
    float*                nrm;
};

// ---------------------------------------------------------------------------
// conv_w: convert one 16384-f32 chunk of W to bf16 (iters [it0,it1), 256 thr).
// Overlapped with L2-bound NS launches so its HBM traffic rides free.
// ---------------------------------------------------------------------------
static __device__ __forceinline__ void conv_w(const float* __restrict__ W,
                                              __hip_bfloat16* __restrict__ Wbf,
                                              int cb, int it0, int it1, int tid)
{
    const size_t base = (size_t)cb * 4096;   // in f32x4 units
    for (int it = it0; it < it1; ++it) {
        const size_t idx = (base + (size_t)it * 256 + tid) * 4;
        const f32x4 v = *reinterpret_cast<const f32x4*>(W + idx);
        ushort4 o;
        o.x = f2bfu(v[0]); o.y = f2bfu(v[1]); o.z = f2bfu(v[2]); o.w = f2bfu(v[3]);
        *reinterpret_cast<ushort4*>(Wbf + idx) = o;
    }
}

// ---------------------------------------------------------------------------
// Kernel 1: per-(b,c) row centering + bf16 cast (pad to MP) + rowsq.
// Tail blocks (>=4096) convert the first 296 W chunks.
// ---------------------------------------------------------------------------
__global__ __launch_bounds__(256) void k_center(const float* __restrict__ feat,
                                                __hip_bfloat16* __restrict__ xcb,
                                                float* __restrict__ rowsq,
                                                const float* __restrict__ W,
                                                __hip_bfloat16* __restrict__ Wbf)
{
    if (blockIdx.x >= 4096) {
        conv_w(W, Wbf, blockIdx.x - 4096, 0, 16, threadIdx.x);
        return;
    }
    const int row = blockIdx.x * 4 + (threadIdx.x >> 6);   // [0, 64*256)
    const int l = threadIdx.x & 63;
    const float* src = feat + (size_t)row * MHW;
    float v0 = src[l];
    float v1 = src[l + 64];
    float v2 = src[l + 128];
    float v3 = (l + 192 < MHW) ? src[l + 192] : 0.0f;
    float s = v0 + v1 + v2 + v3;
    #pragma unroll
    for (int o = 32; o >= 1; o >>= 1) s += __shfl_xor(s, o, 64);
    const float mean = s * (1.0f / MHW);
    v0 -= mean; v1 -= mean; v2 -= mean;
    v3 = (l + 192 < MHW) ? (v3 - mean) : 0.0f;
    float sq = v0*v0 + v1*v1 + v2*v2 + v3*v3;
    #pragma unroll
    for (int o = 32; o >= 1; o >>= 1) sq += __shfl_xor(sq, o, 64);
    if (l == 0) rowsq[row] = sq;
    __hip_bfloat16* dst = xcb + (size_t)row * MP;
    dst[l]       = __float2bfloat16(v0);
    dst[l + 64]  = __float2bfloat16(v1);
    dst[l + 128] = __float2bfloat16(v2);
    if (l + 192 < MP) dst[l + 192] = __float2bfloat16(v3);   // includes zero pad
}

// ---------------------------------------------------------------------------
// Kernel 2: batched symmetric matmul, 64x64 upper-triangle tiles (round-3
// proven). out = a*(A@B) + beta*D + gamma*I; B stored exactly symmetric so
// row-reads give B^T cols. Mirror-writes keep symmetry bit-exact.
// Tail blocks (x >= NMM) convert W chunks (split across y when gridDim.y==2).
// ---------------------------------------------------------------------------
template<int KT, bool NORM>
__global__ __launch_bounds__(256) void k_mm(MMOp op0, MMOp op1,
                                            const float* __restrict__ W,
                                            __hip_bfloat16* __restrict__ Wbf,
                                            int conv_base)
{
    const int tid = threadIdx.x;
    if (blockIdx.x >= NMM) {
        const int cb = conv_base + (blockIdx.x - NMM);
        if (gridDim.y == 2) conv_w(W, Wbf, cb, blockIdx.y * 8, blockIdx.y * 8 + 8, tid);
        else                conv_w(W, Wbf, cb, 0, 16, tid);
        return;
    }

    const MMOp op = (blockIdx.y == 0) ? op0 : op1;

    __shared__ __hip_bfloat16 As[64][72];   // pad +8: <=2-way bank alias (free)
    __shared__ __hip_bfloat16 Bs[64][72];
    __shared__ float red[4];
    __shared__ float s_alpha;

    const int b = blockIdx.x / NTRI;
    const int t = blockIdx.x - b * NTRI;
    int ti, tj;
    if (t < 4)      { ti = 0; tj = t; }
    else if (t < 7) { ti = 1; tj = t - 3; }
    else if (t < 9) { ti = 2; tj = t - 5; }
    else            { ti = 3; tj = 3; }

    const int wv = tid >> 6, l = tid & 63;
    const int wr = wv >> 1, wc = wv & 1;
    const int lr = l & 15,  lg = l >> 4;

    if (op.alpha_mode) {
        float v = op.alpha_ptr[b * 256 + tid];
        #pragma unroll
        for (int o = 32; o >= 1; o >>= 1) v += __shfl_xor(v, o, 64);
        if (l == 0) red[wv] = v;
        __syncthreads();
        if (tid == 0) s_alpha = op.alpha_c / (red[0] + red[1] + red[2] + red[3]);
    } else if (tid == 0) {
        s_alpha = op.alpha_c;
    }

    const __hip_bfloat16* Ab = op.A + (size_t)b * (CDIM * KT) + (size_t)ti * 64 * KT;
    const __hip_bfloat16* Bb = op.B + (size_t)b * (CDIM * KT) + (size_t)tj * 64 * KT;

    f32x4 acc[2][2];
    #pragma unroll
    for (int i = 0; i < 2; i++)
        #pragma unroll
        for (int j = 0; j < 2; j++)
            #pragma unroll
            for (int r = 0; r < 4; r++) acc[i][j][r] = 0.0f;

    #pragma unroll
    for (int k0 = 0; k0 < KT; k0 += 64) {
        const int kw   = (KT - k0 >= 64) ? 64 : (KT - k0);   // 64 or 32
        const int segs = kw >> 3;                            // 8 or 4
        __syncthreads();
        for (int u = tid; u < 64 * segs; u += 256) {
            const int row = u / segs;
            const int seg = u - row * segs;
            *reinterpret_cast<u32x4*>(&As[row][seg * 8]) =
                *reinterpret_cast<const u32x4*>(Ab + (size_t)row * KT + k0 + seg * 8);
            *reinterpret_cast<u32x4*>(&Bs[row][seg * 8]) =
                *reinterpret_cast<const u32x4*>(Bb + (size_t)row * KT + k0 + seg * 8);
        }
        __syncthreads();
        const int nks = kw >> 5;   // 2 or 1
        for (int ks = 0; ks < nks; ks++) {
            short8_t af[2], bfr[2];
            #pragma unroll
            for (int i = 0; i < 2; i++)
                af[i] = *reinterpret_cast<const short8_t*>(&As[wr * 32 + i * 16 + lr][ks * 32 + lg * 8]);
            #pragma unroll
            for (int j = 0; j < 2; j++)
                bfr[j] = *reinterpret_cast<const short8_t*>(&Bs[wc * 32 + j * 16 + lr][ks * 32 + lg * 8]);
            #pragma unroll
            for (int i = 0; i < 2; i++)
                #pragma unroll
                for (int j = 0; j < 2; j++)
                    acc[i][j] = __builtin_amdgcn_mfma_f32_16x16x32_bf16(af[i], bfr[j], acc[i][j], 0, 0, 0);
        }
    }

    const float a = s_alpha;
    __hip_bfloat16* ob = op.out + (size_t)b * CC;
    const __hip_bfloat16* Db = op.D ? (op.D + (size_t)b * CC) : nullptr;
    float ns = 0.0f;
    #pragma unroll
    for (int i = 0; i < 2; i++) {
        #pragma unroll
        for (int j = 0; j < 2; j++) {
            #pragma unroll
            for (int r = 0; r < 4; r++) {
                const int grow = ti * 64 + wr * 32 + i * 16 + lg * 4 + r;
                const int gcol = tj * 64 + wc * 32 + j * 16 + lr;
                float v = a * acc[i][j][r];
                if (Db) v += op.beta * __bfloat162float(Db[grow * 256 + gcol]);
                if (grow == gcol) v += op.gamma;
                const __hip_bfloat16 hv = __float2bfloat16(v);
                ob[grow * 256 + gcol] = hv;
                if (ti != tj) ob[gcol * 256 + grow] = hv;   // exact-symmetry mirror
                if (NORM) {
                    const float fv = __bfloat162float(hv);
                    ns += ((ti != tj) ? 2.0f : 1.0f) * fv * fv;
                }
            }
        }
    }
    if constexpr (NORM) {
        #pragma unroll
        for (int o = 32; o >= 1; o >>= 1) ns += __shfl_xor(ns, o, 64);
        __syncthreads();
        if (l == 0) red[wv] = ns;
        __syncthreads();
        if (tid == 0) op.nrm[b * NTRI + t] = red[0] + red[1] + red[2] + red[3];
    }
}

// ---------------------------------------------------------------------------
// Kernel 3: projection vs bf16 W (half the HBM of f32). Split-K (64,8) grid,
// block K-chunk 1024 (4 waves x 256), cross-wave LDS reduce -> upart[ks].
// ---------------------------------------------------------------------------
__global__ __launch_bounds__(256) void k_proj2(const __hip_bfloat16* __restrict__ flat,
                                               const __hip_bfloat16* __restrict__ Wbf,
                                               float* __restrict__ upart)
{
    __shared__ float racc[2][64][65];
    const int ks = blockIdx.x, et = blockIdx.y;
    const int tid = threadIdx.x, wv = tid >> 6, l = tid & 63;
    const int lr = l & 15, lg = l >> 4;
    const int kbase = ks * 1024 + wv * 256;

    f32x4 acc[4][4];
    #pragma unroll
    for (int i = 0; i < 4; i++)
        #pragma unroll
        for (int j = 0; j < 4; j++)
            #pragma unroll
            for (int r = 0; r < 4; r++) acc[i][j][r] = 0.0f;

    for (int kk = 0; kk < 256; kk += 32) {
        const int k = kbase + kk + lg * 8;
        short8_t af[4], bfr[4];
        #pragma unroll
        for (int i = 0; i < 4; i++)
            af[i] = *reinterpret_cast<const short8_t*>(flat + (size_t)(i * 16 + lr) * CC + k);
        #pragma unroll
        for (int j = 0; j < 4; j++)
            bfr[j] = *reinterpret_cast<const short8_t*>(Wbf + (size_t)(et * 64 + j * 16 + lr) * CC + k);
        #pragma unroll
        for (int i = 0; i < 4; i++)
            #pragma unroll
            for (int j = 0; j < 4; j++)
                acc[i][j] = __builtin_amdgcn_mfma_f32_16x16x32_bf16(af[i], bfr[j], acc[i][j], 0, 0, 0);
    }

    if (wv >= 2) {
        #pragma unroll
        for (int i = 0; i < 4; i++)
            #pragma unroll
            for (int j = 0; j < 4; j++)
                #pragma unroll
                for (int r = 0; r < 4; r++)
                    racc[wv - 2][i * 16 + lg * 4 + r][j * 16 + lr] = acc[i][j][r];
    }
    __syncthreads();
    if (wv < 2) {
        #pragma unroll
        for (int i = 0; i < 4; i++)
            #pragma unroll
            for (int j = 0; j < 4; j++)
                #pragma unroll
                for (int r = 0; r < 4; r++)
                    racc[wv][i * 16 + lg * 4 + r][j * 16 + lr] += acc[i][j][r];
    }
    __syncthreads();
    float* ub = upart + (size_t)ks * (64 * EDIM);
    #pragma unroll
    for (int q = 0; q < 16; q++) {
        const int idx = q * 256 + tid;
        const int x = idx >> 6, y = idx & 63;
        ub[(size_t)x * EDIM + et * 64 + y] = racc[0][x][y] + racc[1][x][y];
    }
}

// ---------------------------------------------------------------------------
// Kernel 4: reduce 64 K-partials, 1/||Y3||_F, +bias, BN, final L2 norm.
// ---------------------------------------------------------------------------
__global__ __launch_bounds__(256) void k_fin(const float* __restrict__ upart,
                                             const float* __restrict__ nrmp,
                                             const float* __restrict__ bias,
                                             const float* __restrict__ gma,
                                             const float* __restrict__ bta,
                                             const float* __restrict__ mu,
                                             const float* __restrict__ var,
                                             float* __restrict__ out)
{
    __shared__ float wsum[4];
    const int bb = blockIdx.x;
    const int tid = threadIdx.x, wv = tid >> 6, l = tid & 63;
    const int e0 = tid, e1 = tid + 256;
    float u0 = 0.0f, u1 = 0.0f;
    for (int p = 0; p < 64; ++p) {
        const float* up = upart + ((size_t)p * 64 + bb) * EDIM;
        u0 += up[e0]; u1 += up[e1];
    }
    float fro = 0.0f;
    #pragma unroll
    for (int q = 0; q < NTRI; ++q) fro += nrmp[bb * NTRI + q];
    const float s = 1.0f / fmaxf(sqrtf(fro), 1e-12f);
    const float emb0 = s * u0 + bias[e0];
    const float emb1 = s * u1 + bias[e1];
    const float v0 = (emb0 - mu[e0]) * rsqrtf(var[e0] + 1e-5f) * gma[e0] + bta[e0];
    const float v1 = (emb1 - mu[e1]) * rsqrtf(var[e1] + 1e-5f) * gma[e1] + bta[e1];
    float sq = v0 * v0 + v1 * v1;
    #pragma unroll
    for (int o = 32; o >= 1; o >>= 1) sq += __shfl_xor(sq, o, 64);
    if (l == 0) wsum[wv] = sq;
    __syncthreads();
    const float tot = wsum[0] + wsum[1] + wsum[2] + wsum[3];
    const float rn = 1.0f / fmaxf(sqrtf(tot), 1e-12f);
    out[(size_t)bb * EDIM + e0] = v0 * rn;
    out[(size_t)bb * EDIM + e1] = v1 * rn;
}

// ---------------------------------------------------------------------------
extern "C" void kernel_launch(void* const* d_in, const int* in_sizes, int n_in,
                              void* d_out, int out_size, void* d_ws, size_t ws_size,
                              hipStream_t stream)
{
    const float* feat = (const float*)d_in[0];
    const float* W    = (const float*)d_in[1];
    const float* bias = (const float*)d_in[2];
    const float* gma  = (const float*)d_in[3];
    const float* bta  = (const float*)d_in[4];
    const float* mu   = (const float*)d_in[5];
    const float* var  = (const float*)d_in[6];
    float* out = (float*)d_out;

    char* ws = (char*)d_ws;
    constexpr size_t XCB_BYTES = (size_t)BATCH * CDIM * MP * 2;   //  7,340,032
    constexpr size_t MATB      = (size_t)BATCH * CC * 2;          //  8,388,608
    constexpr size_t WBF_BYTES = (size_t)CC * EDIM * 2;           // 67,108,864
    constexpr size_t OFF_ROWSQ = 4096;
    constexpr size_t OFF_XCB   = OFF_ROWSQ + (size_t)BATCH * CDIM * 4;
    constexpr size_t OFF_M     = OFF_XCB + XCB_BYTES;
    constexpr size_t OFF_WBF   = OFF_M + 5 * MATB;
    constexpr size_t OFF_UP    = OFF_WBF + WBF_BYTES;
    constexpr size_t NEEDED    = OFF_UP + (size_t)64 * 64 * EDIM * 4;  // ~133 MB
    if (ws_size < NEEDED) return;

    float* nrmp  = (float*)(ws + 1024);          // 640 floats
    float* rowsq = (float*)(ws + OFF_ROWSQ);     // 16384 floats
    __hip_bfloat16* xcb = (__hip_bfloat16*)(ws + OFF_XCB);
    __hip_bfloat16* M0  = (__hip_bfloat16*)(ws + OFF_M + 0 * MATB);
    __hip_bfloat16* M1  = (__hip_bfloat16*)(ws + OFF_M + 1 * MATB);
    __hip_bfloat16* M2  = (__hip_bfloat16*)(ws + OFF_M + 2 * MATB);
    __hip_bfloat16* M3  = (__hip_bfloat16*)(ws + OFF_M + 3 * MATB);
    __hip_bfloat16* M4  = (__hip_bfloat16*)(ws + OFF_M + 4 * MATB);
    __hip_bfloat16* Wbf = (__hip_bfloat16*)(ws + OFF_WBF);
    float* upart = (float*)(ws + OFF_UP);

    // W-conversion chunk schedule: 296 in k_center, 292 in each of 6 k_mm.
    k_center<<<dim3(4096 + 296), 256, 0, stream>>>(feat, xcb, rowsq, W, Wbf);

    const dim3 g1(NMM + 292, 1), g2(NMM + 292, 2), blk(256);
    MMOp nop = {};

    // y  = (1/tr) * xc @ xc^T                          -> M0
    MMOp cov = {xcb, xcb, nullptr, M0, rowsq, 1, 1.0f, 0.0f, 0.0f, nullptr};
    k_mm<MP, false><<<g1, blk, 0, stream>>>(cov, nop, W, Wbf, 296);
    // Y1 = -0.5*y@y + 1.5*y                            -> M1
    MMOp y1 = {M0, M0, M0, M1, nullptr, 0, -0.5f, 1.5f, 0.0f, nullptr};
    k_mm<256, false><<<g1, blk, 0, stream>>>(y1, nop, W, Wbf, 588);
    // T2 = 0.5*y@Y1 - 1.5*Y1 + 3I                      -> M2
    MMOp t2 = {M0, M1, M1, M2, nullptr, 0, 0.5f, -1.5f, 3.0f, nullptr};
    k_mm<256, false><<<g1, blk, 0, stream>>>(t2, nop, W, Wbf, 880);
    // Y2 = 0.5*Y1@T2 -> M3   ||   Z2 = -0.25*T2@y + 0.75*T2 -> M4   (merged)
    MMOp y2 = {M1, M2, nullptr, M3, nullptr, 0, 0.5f, 0.0f, 0.0f, nullptr};
    MMOp z2 = {M2, M0, M2, M4, nullptr, 0, -0.25f, 0.75f, 0.0f, nullptr};
    k_mm<256, false><<<g2, blk, 0, stream>>>(y2, z2, W, Wbf, 1172);
    // T3 = -Z2@Y2 + 3I                                 -> M1
    MMOp t3 = {M4, M3, nullptr, M1, nullptr, 0, -1.0f, 0.0f, 3.0f, nullptr};
    k_mm<256, false><<<g1, blk, 0, stream>>>(t3, nop, W, Wbf, 1464);
    // Y3 = 0.5*Y2@T3  (+ Frobenius norm^2 partials)    -> M2
    MMOp y3 = {M3, M1, nullptr, M2, nullptr, 0, 0.5f, 0.0f, 0.0f, nrmp};
    k_mm<256, true ><<<g1, blk, 0, stream>>>(y3, nop, W, Wbf, 1756);

    k_proj2<<<dim3(64, 8), blk, 0, stream>>>(M2, Wbf, upart);
    k_fin<<<dim3(64), blk, 0, stream>>>(upart, nrmp, bias, gma, bta, mu, var, out);
}

// Round 9
// 115.074 us; speedup vs baseline: 2.9794x; 1.3712x over previous
//
#include <hip/hip_runtime.h>
#include <hip/hip_bf16.h>

#define BATCH 64
#define CDIM  256
#define MHW   196
#define MP    224      // padded K for covariance (multiple of 32)
#define EDIM  512
#define CC    65536    // CDIM*CDIM
#define NTRI  10       // upper-triangle 64x64 tiles of a 256x256 matrix
#define NMM   (BATCH * NTRI)   // 640 mm blocks per step

typedef __attribute__((ext_vector_type(8))) short short8_t;   // 8 x bf16 MFMA frag
typedef __attribute__((ext_vector_type(4))) float f32x4;
typedef __attribute__((ext_vector_type(4))) unsigned int u32x4;

static __device__ __forceinline__ short f2bf(float f) {
    __hip_bfloat16 h = __float2bfloat16(f);
    return (short)__builtin_bit_cast(unsigned short, h);
}

struct MMOp {
    const __hip_bfloat16* A;
    const __hip_bfloat16* B;
    const __hip_bfloat16* D;
    __hip_bfloat16*       out;
    const float*          alpha_ptr;   // mode!=0: rowsq base, a = alpha_c / sum256
    int                   alpha_mode;
    float                 alpha_c, beta, gamma;
    float*                nrm;
};

// ---------------------------------------------------------------------------
// Kernel 1: per-(b,c) row centering + bf16 cast (pad to MP) + rowsq.
// XCD swizzle: blockIdx = r4*64 + b -> XCD(b%8) owns batch b's xcb rows,
// matching the mm kernels' placement so cov reads hit the local L2.
// ---------------------------------------------------------------------------
__global__ __launch_bounds__(256) void k_center(const float* __restrict__ feat,
                                                __hip_bfloat16* __restrict__ xcb,
                                                float* __restrict__ rowsq)
{
    const int b  = blockIdx.x & 63;
    const int r4 = blockIdx.x >> 6;
    const int row = b * 256 + r4 * 4 + (threadIdx.x >> 6);
    const int l = threadIdx.x & 63;
    const float* src = feat + (size_t)row * MHW;
    float v0 = src[l];
    float v1 = src[l + 64];
    float v2 = src[l + 128];
    float v3 = (l + 192 < MHW) ? src[l + 192] : 0.0f;
    float s = v0 + v1 + v2 + v3;
    #pragma unroll
    for (int o = 32; o >= 1; o >>= 1) s += __shfl_xor(s, o, 64);
    const float mean = s * (1.0f / MHW);
    v0 -= mean; v1 -= mean; v2 -= mean;
    v3 = (l + 192 < MHW) ? (v3 - mean) : 0.0f;
    float sq = v0*v0 + v1*v1 + v2*v2 + v3*v3;
    #pragma unroll
    for (int o = 32; o >= 1; o >>= 1) sq += __shfl_xor(sq, o, 64);
    if (l == 0) rowsq[row] = sq;
    __hip_bfloat16* dst = xcb + (size_t)row * MP;
    dst[l]       = __float2bfloat16(v0);
    dst[l + 64]  = __float2bfloat16(v1);
    dst[l + 128] = __float2bfloat16(v2);
    if (l + 192 < MP) dst[l + 192] = __float2bfloat16(v3);   // includes zero pad
}

// ---------------------------------------------------------------------------
// Kernel 2: batched symmetric matmul, 64x64 upper-triangle tiles.
// out = a*(A@B) + beta*D + gamma*I; B stored exactly symmetric (mirror
// writes) so row-reads give B^T columns.
// XCD swizzle: blockIdx.x = t*64 + b -> all 10 tiles of batch b land on
// XCD b%8 in EVERY launch; inter-step 128KB/batch matrices stay in the
// local 4MB L2 (8 batches x ~4 live matrices x 128KB = 4MB) instead of
// bouncing through L3.
// ---------------------------------------------------------------------------
template<int KT, bool NORM>
__global__ __launch_bounds__(256) void k_mm(MMOp op0, MMOp op1)
{
    const MMOp op = (blockIdx.y == 0) ? op0 : op1;

    __shared__ __hip_bfloat16 As[64][72];   // pad +8: <=2-way bank alias (free)
    __shared__ __hip_bfloat16 Bs[64][72];
    __shared__ float red[4];
    __shared__ float s_alpha;

    const int b = blockIdx.x & 63;
    const int t = blockIdx.x >> 6;
    int ti, tj;
    if (t < 4)      { ti = 0; tj = t; }
    else if (t < 7) { ti = 1; tj = t - 3; }
    else if (t < 9) { ti = 2; tj = t - 5; }
    else            { ti = 3; tj = 3; }

    const int tid = threadIdx.x;
    const int wv = tid >> 6, l = tid & 63;
    const int wr = wv >> 1, wc = wv & 1;
    const int lr = l & 15,  lg = l >> 4;

    if (op.alpha_mode) {
        float v = op.alpha_ptr[b * 256 + tid];
        #pragma unroll
        for (int o = 32; o >= 1; o >>= 1) v += __shfl_xor(v, o, 64);
        if (l == 0) red[wv] = v;
        __syncthreads();
        if (tid == 0) s_alpha = op.alpha_c / (red[0] + red[1] + red[2] + red[3]);
    } else if (tid == 0) {
        s_alpha = op.alpha_c;
    }

    const __hip_bfloat16* Ab = op.A + (size_t)b * (CDIM * KT) + (size_t)ti * 64 * KT;
    const __hip_bfloat16* Bb = op.B + (size_t)b * (CDIM * KT) + (size_t)tj * 64 * KT;

    f32x4 acc[2][2];
    #pragma unroll
    for (int i = 0; i < 2; i++)
        #pragma unroll
        for (int j = 0; j < 2; j++)
            #pragma unroll
            for (int r = 0; r < 4; r++) acc[i][j][r] = 0.0f;

    #pragma unroll
    for (int k0 = 0; k0 < KT; k0 += 64) {
        const int kw   = (KT - k0 >= 64) ? 64 : (KT - k0);   // 64 or 32
        const int segs = kw >> 3;                            // 8 or 4
        __syncthreads();
        for (int u = tid; u < 64 * segs; u += 256) {
            const int row = u / segs;
            const int seg = u - row * segs;
            *reinterpret_cast<u32x4*>(&As[row][seg * 8]) =
                *reinterpret_cast<const u32x4*>(Ab + (size_t)row * KT + k0 + seg * 8);
            *reinterpret_cast<u32x4*>(&Bs[row][seg * 8]) =
                *reinterpret_cast<const u32x4*>(Bb + (size_t)row * KT + k0 + seg * 8);
        }
        __syncthreads();
        const int nks = kw >> 5;   // 2 or 1
        for (int ks = 0; ks < nks; ks++) {
            short8_t af[2], bfr[2];
            #pragma unroll
            for (int i = 0; i < 2; i++)
                af[i] = *reinterpret_cast<const short8_t*>(&As[wr * 32 + i * 16 + lr][ks * 32 + lg * 8]);
            #pragma unroll
            for (int j = 0; j < 2; j++)
                bfr[j] = *reinterpret_cast<const short8_t*>(&Bs[wc * 32 + j * 16 + lr][ks * 32 + lg * 8]);
            #pragma unroll
            for (int i = 0; i < 2; i++)
                #pragma unroll
                for (int j = 0; j < 2; j++)
                    acc[i][j] = __builtin_amdgcn_mfma_f32_16x16x32_bf16(af[i], bfr[j], acc[i][j], 0, 0, 0);
        }
    }

    const float a = s_alpha;
    __hip_bfloat16* ob = op.out + (size_t)b * CC;
    const __hip_bfloat16* Db = op.D ? (op.D + (size_t)b * CC) : nullptr;
    float ns = 0.0f;
    #pragma unroll
    for (int i = 0; i < 2; i++) {
        #pragma unroll
        for (int j = 0; j < 2; j++) {
            #pragma unroll
            for (int r = 0; r < 4; r++) {
                const int grow = ti * 64 + wr * 32 + i * 16 + lg * 4 + r;
                const int gcol = tj * 64 + wc * 32 + j * 16 + lr;
                float v = a * acc[i][j][r];
                if (Db) v += op.beta * __bfloat162float(Db[grow * 256 + gcol]);
                if (grow == gcol) v += op.gamma;
                const __hip_bfloat16 hv = __float2bfloat16(v);
                ob[grow * 256 + gcol] = hv;
                if (ti != tj) ob[gcol * 256 + grow] = hv;   // exact-symmetry mirror
                if (NORM) {
                    const float fv = __bfloat162float(hv);
                    ns += ((ti != tj) ? 2.0f : 1.0f) * fv * fv;
                }
            }
        }
    }
    if constexpr (NORM) {
        #pragma unroll
        for (int o = 32; o >= 1; o >>= 1) ns += __shfl_xor(ns, o, 64);
        __syncthreads();
        if (l == 0) red[wv] = ns;
        __syncthreads();
        if (tid == 0) op.nrm[b * NTRI + t] = red[0] + red[1] + red[2] + red[3];
    }
}

// ---------------------------------------------------------------------------
// Kernel 3: projection u[b,e] = sum_k flat[b,k] * W[e,k]. W read ONCE as f32
// (round-8 proved converting it costs 201MB extra traffic, never hidden).
// Split-K grid (64,8): 2048 waves = 8/CU for HBM streaming depth; block
// K-chunk 1024 (4 waves x 256), cross-wave LDS reduce -> upart[64][64][512].
// ---------------------------------------------------------------------------
__global__ __launch_bounds__(256) void k_proj(const __hip_bfloat16* __restrict__ flat,
                                              const float* __restrict__ W,
                                              float* __restrict__ upart)
{
    __shared__ float racc[2][64][65];
    const int ks = blockIdx.x, et = blockIdx.y;
    const int tid = threadIdx.x, wv = tid >> 6, l = tid & 63;
    const int lr = l & 15, lg = l >> 4;
    const int kbase = ks * 1024 + wv * 256;

    f32x4 acc[4][4];
    #pragma unroll
    for (int i = 0; i < 4; i++)
        #pragma unroll
        for (int j = 0; j < 4; j++)
            #pragma unroll
            for (int r = 0; r < 4; r++) acc[i][j][r] = 0.0f;

    for (int kk = 0; kk < 256; kk += 32) {
        const int k = kbase + kk + lg * 8;
        short8_t af[4];
        #pragma unroll
        for (int i = 0; i < 4; i++)
            af[i] = *reinterpret_cast<const short8_t*>(flat + (size_t)(i * 16 + lr) * CC + k);
        short8_t bfr[4];
        #pragma unroll
        for (int j = 0; j < 4; j++) {
            const f32x4* wp = reinterpret_cast<const f32x4*>(W + (size_t)(et * 64 + j * 16 + lr) * CC + k);
            const f32x4 w0 = wp[0], w1 = wp[1];
            short8_t s;
            s[0] = f2bf(w0[0]); s[1] = f2bf(w0[1]); s[2] = f2bf(w0[2]); s[3] = f2bf(w0[3]);
            s[4] = f2bf(w1[0]); s[5] = f2bf(w1[1]); s[6] = f2bf(w1[2]); s[7] = f2bf(w1[3]);
            bfr[j] = s;
        }
        #pragma unroll
        for (int i = 0; i < 4; i++)
            #pragma unroll
            for (int j = 0; j < 4; j++)
                acc[i][j] = __builtin_amdgcn_mfma_f32_16x16x32_bf16(af[i], bfr[j], acc[i][j], 0, 0, 0);
    }

    if (wv >= 2) {
        #pragma unroll
        for (int i = 0; i < 4; i++)
            #pragma unroll
            for (int j = 0; j < 4; j++)
                #pragma unroll
                for (int r = 0; r < 4; r++)
                    racc[wv - 2][i * 16 + lg * 4 + r][j * 16 + lr] = acc[i][j][r];
    }
    __syncthreads();
    if (wv < 2) {
        #pragma unroll
        for (int i = 0; i < 4; i++)
            #pragma unroll
            for (int j = 0; j < 4; j++)
                #pragma unroll
                for (int r = 0; r < 4; r++)
                    racc[wv][i * 16 + lg * 4 + r][j * 16 + lr] += acc[i][j][r];
    }
    __syncthreads();
    float* ub = upart + (size_t)ks * (64 * EDIM);
    #pragma unroll
    for (int q = 0; q < 16; q++) {
        const int idx = q * 256 + tid;
        const int x = idx >> 6, y = idx & 63;
        ub[(size_t)x * EDIM + et * 64 + y] = racc[0][x][y] + racc[1][x][y];
    }
}

// ---------------------------------------------------------------------------
// Kernel 4: reduce 64 K-partials, 1/||Y3||_F, +bias, BN, final L2 norm.
// ---------------------------------------------------------------------------
__global__ __launch_bounds__(256) void k_fin(const float* __restrict__ upart,
                                             const float* __restrict__ nrmp,
                                             const float* __restrict__ bias,
                                             const float* __restrict__ gma,
                                             const float* __restrict__ bta,
                                             const float* __restrict__ mu,
                                             const float* __restrict__ var,
                                             float* __restrict__ out)
{
    __shared__ float wsum[4];
    const int bb = blockIdx.x;
    const int tid = threadIdx.x, wv = tid >> 6, l = tid & 63;
    const int e0 = tid, e1 = tid + 256;
    float u0 = 0.0f, u1 = 0.0f;
    for (int p = 0; p < 64; ++p) {
        const float* up = upart + ((size_t)p * 64 + bb) * EDIM;
        u0 += up[e0]; u1 += up[e1];
    }
    float fro = 0.0f;
    #pragma unroll
    for (int q = 0; q < NTRI; ++q) fro += nrmp[bb * NTRI + q];
    const float s = 1.0f / fmaxf(sqrtf(fro), 1e-12f);
    const float emb0 = s * u0 + bias[e0];
    const float emb1 = s * u1 + bias[e1];
    const float v0 = (emb0 - mu[e0]) * rsqrtf(var[e0] + 1e-5f) * gma[e0] + bta[e0];
    const float v1 = (emb1 - mu[e1]) * rsqrtf(var[e1] + 1e-5f) * gma[e1] + bta[e1];
    float sq = v0 * v0 + v1 * v1;
    #pragma unroll
    for (int o = 32; o >= 1; o >>= 1) sq += __shfl_xor(sq, o, 64);
    if (l == 0) wsum[wv] = sq;
    __syncthreads();
    const float tot = wsum[0] + wsum[1] + wsum[2] + wsum[3];
    const float rn = 1.0f / fmaxf(sqrtf(tot), 1e-12f);
    out[(size_t)bb * EDIM + e0] = v0 * rn;
    out[(size_t)bb * EDIM + e1] = v1 * rn;
}

// ---------------------------------------------------------------------------
extern "C" void kernel_launch(void* const* d_in, const int* in_sizes, int n_in,
                              void* d_out, int out_size, void* d_ws, size_t ws_size,
                              hipStream_t stream)
{
    const float* feat = (const float*)d_in[0];
    const float* W    = (const float*)d_in[1];
    const float* bias = (const float*)d_in[2];
    const float* gma  = (const float*)d_in[3];
    const float* bta  = (const float*)d_in[4];
    const float* mu   = (const float*)d_in[5];
    const float* var  = (const float*)d_in[6];
    float* out = (float*)d_out;

    char* ws = (char*)d_ws;
    constexpr size_t XCB_BYTES = (size_t)BATCH * CDIM * MP * 2;   //  7,340,032
    constexpr size_t MATB      = (size_t)BATCH * CC * 2;          //  8,388,608
    constexpr size_t OFF_ROWSQ = 4096;
    constexpr size_t OFF_XCB   = OFF_ROWSQ + (size_t)BATCH * CDIM * 4;
    constexpr size_t OFF_M     = OFF_XCB + XCB_BYTES;
    constexpr size_t OFF_UP    = OFF_M + 5 * MATB;
    constexpr size_t NEEDED    = OFF_UP + (size_t)64 * 64 * EDIM * 4;  // ~66 MB
    if (ws_size < NEEDED) return;

    float* nrmp  = (float*)(ws + 1024);          // 640 floats
    float* rowsq = (float*)(ws + OFF_ROWSQ);     // 16384 floats
    __hip_bfloat16* xcb = (__hip_bfloat16*)(ws + OFF_XCB);
    __hip_bfloat16* M0  = (__hip_bfloat16*)(ws + OFF_M + 0 * MATB);
    __hip_bfloat16* M1  = (__hip_bfloat16*)(ws + OFF_M + 1 * MATB);
    __hip_bfloat16* M2  = (__hip_bfloat16*)(ws + OFF_M + 2 * MATB);
    __hip_bfloat16* M3  = (__hip_bfloat16*)(ws + OFF_M + 3 * MATB);
    __hip_bfloat16* M4  = (__hip_bfloat16*)(ws + OFF_M + 4 * MATB);
    float* upart = (float*)(ws + OFF_UP);

    k_center<<<dim3(4096), 256, 0, stream>>>(feat, xcb, rowsq);

    const dim3 g1(NMM, 1), g2(NMM, 2), blk(256);
    MMOp nop = {};

    // y  = (1/tr) * xc @ xc^T                          -> M0
    MMOp cov = {xcb, xcb, nullptr, M0, rowsq, 1, 1.0f, 0.0f, 0.0f, nullptr};
    k_mm<MP, false><<<g1, blk, 0, stream>>>(cov, nop);
    // Y1 = -0.5*y@y + 1.5*y                            -> M1
    MMOp y1 = {M0, M0, M0, M1, nullptr, 0, -0.5f, 1.5f, 0.0f, nullptr};
    k_mm<256, false><<<g1, blk, 0, stream>>>(y1, nop);
    // T2 = 0.5*y@Y1 - 1.5*Y1 + 3I                      -> M2
    MMOp t2 = {M0, M1, M1, M2, nullptr, 0, 0.5f, -1.5f, 3.0f, nullptr};
    k_mm<256, false><<<g1, blk, 0, stream>>>(t2, nop);
    // Y2 = 0.5*Y1@T2 -> M3   ||   Z2 = -0.25*T2@y + 0.75*T2 -> M4   (merged)
    MMOp y2 = {M1, M2, nullptr, M3, nullptr, 0, 0.5f, 0.0f, 0.0f, nullptr};
    MMOp z2 = {M2, M0, M2, M4, nullptr, 0, -0.25f, 0.75f, 0.0f, nullptr};
    k_mm<256, false><<<g2, blk, 0, stream>>>(y2, z2);
    // T3 = -Z2@Y2 + 3I                                 -> M1
    MMOp t3 = {M4, M3, nullptr, M1, nullptr, 0, -1.0f, 0.0f, 3.0f, nullptr};
    k_mm<256, false><<<g1, blk, 0, stream>>>(t3, nop);
    // Y3 = 0.5*Y2@T3  (+ Frobenius norm^2 partials)    -> M2
    MMOp y3 = {M3, M1, nullptr, M2, nullptr, 0, 0.5f, 0.0f, 0.0f, nrmp};
    k_mm<256, true ><<<g1, blk, 0, stream>>>(y3, nop);

    k_proj<<<dim3(64, 8), blk, 0, stream>>>(M2, W, upart);
    k_fin<<<dim3(64), blk, 0, stream>>>(upart, nrmp, bias, gma, bta, mu, var, out);
}